// Round 7
// baseline (651.842 us; speedup 1.0000x reference)
//
#include <hip/hip_runtime.h>

#define B_TOK 32768
#define D_IN  256
#define H_LAT 8192
#define TOPK  32
#define MT    64          // rows per block
#define NT    128         // h-cols per chunk
#define NCH   (H_LAT / NT)
#define CAP   144         // candidate pool per row (thr=2.3sigma -> lambda~90)
#define DELTA 0.016f      // exact-rescore window; covers bf16-GEMM + key-trunc err

typedef __attribute__((ext_vector_type(4))) float f32x4;
typedef __attribute__((ext_vector_type(8))) short bf16x8;

__device__ __forceinline__ unsigned short f2bf(float f) {   // RNE fp32->bf16
    unsigned u = __float_as_uint(f);
    return (unsigned short)((u + 0x7fffu + ((u >> 16) & 1u)) >> 16);
}
__device__ __forceinline__ float bf2f(unsigned short u) {
    return __uint_as_float((unsigned)u << 16);
}

// Kernel A: W_enc fp32 -> bf16 SWIZZLED to MFMA-fragment order (+ sum W^2);
// W_dec fp32 -> bf16 linear (decoder copy).
// Swizzled layout: dst[((ct16*8 + c8)*64 + lane)*8 + e] =
//   W[ct16*16 + (lane&15)][c8*32 + (lane>>4)*8 + e]
__global__ __launch_bounds__(256)
void conv_kernel(const float* __restrict__ W, unsigned short* __restrict__ Wbf,
                 float* __restrict__ s2w, const float* __restrict__ Wd,
                 unsigned short* __restrict__ Wdbf) {
    const int total4 = (H_LAT * D_IN) / 4;
    float acc = 0.0f;
    for (int j = blockIdx.x * blockDim.x + threadIdx.x; j < total4;
         j += gridDim.x * blockDim.x) {
        const int e4   = j & 1;                 // which half of the 8-elem frag
        const int lane = (j >> 1) & 63;
        const int c8   = (j >> 7) & 7;
        const int ct16 = j >> 10;               // 16-col tile, 0..511
        const int h = ct16 * 16 + (lane & 15);
        const int k = c8 * 32 + (lane >> 4) * 8 + e4 * 4;
        const float4 v = *(const float4*)(W + (size_t)h * D_IN + k);
        acc += v.x * v.x + v.y * v.y + v.z * v.z + v.w * v.w;
        ushort4 o;
        o.x = f2bf(v.x); o.y = f2bf(v.y); o.z = f2bf(v.z); o.w = f2bf(v.w);
        ((ushort4*)Wbf)[j] = o;                 // coalesced write
    }
    for (int i = blockIdx.x * blockDim.x + threadIdx.x; i < total4;
         i += gridDim.x * blockDim.x) {
        const float4 v = ((const float4*)Wd)[i];
        ushort4 o;
        o.x = f2bf(v.x); o.y = f2bf(v.y); o.z = f2bf(v.z); o.w = f2bf(v.w);
        ((ushort4*)Wdbf)[i] = o;
    }
#pragma unroll
    for (int off = 32; off > 0; off >>= 1) acc += __shfl_down(acc, off, 64);
    if ((threadIdx.x & 63) == 0) atomicAdd(s2w, acc);
}

// Kernel B: R6 structure (512 thr, 8 waves x 16-col strips, 4 waves/SIMD) with:
//  - A in LDS stored in MFMA-FRAGMENT order: phase-1 A-reads are base+lane*16B
//    with immediate offsets -> zero bank conflicts (was 22.2M conflict cycles)
//  - uint-ordered keys: (f32bits & ~0x1FFF) | (8191-col), 2 VALU vs f2bf's 5
//  - cross-chunk-paired collection: 16 atomics/group (covers both chunks)
__global__ __launch_bounds__(512, 4)
void sae_main(const float* __restrict__ x, const float* __restrict__ W_enc,
              const float* __restrict__ b_enc, const float* __restrict__ W_dec,
              const float* __restrict__ b_dec, float* __restrict__ out,
              const unsigned short* __restrict__ Wbf, const float* __restrict__ s2w,
              const unsigned short* __restrict__ Wdbf) {
    // smem: [0, 32768)     A_frag[32][512] ushort  (UNION ext_i 8KB + ext_v 16KB)
    //       [32768, 69632) pool[64][144]
    __shared__ __align__(16) char smem[32768 + MT * CAP * 4];
    __shared__ int   cnt[MT];
    __shared__ float thr[MT];

    unsigned short* A = (unsigned short*)smem;
    auto pool = reinterpret_cast<unsigned (*)[CAP]>(smem + 32768);
    unsigned short* ext_i = (unsigned short*)smem;                 // [MT][64] (8 KB)
    float*          ext_v = (float*)(smem + MT * 64 * 2);          // [MT][64] (16 KB)

    const int tid  = threadIdx.x;
    const int row0 = blockIdx.x * MT;
    const int wave = tid >> 6, lane = tid & 63;
    const int l15 = lane & 15, quad = lane >> 4;

    if (tid < MT) { cnt[tid] = 0; thr[tid] = 0.0f; }
    __syncthreads();

    // ---- Phase 0: stage (x - b_dec) -> bf16 LDS in FRAGMENT order ----
    // A[(r>>4)*8 + c8][j*16 + (r&15)] holds elems of row r, k = c8*32 + j*8 ...
    {
        const int r = tid >> 3, q = tid & 7;                // 8 threads/row, 32 k each
        const float* xr = x + (size_t)(row0 + r) * D_IN + q * 32;
        const float* bd = b_dec + q * 32;
        unsigned short* dst = A + ((r >> 4) * 8 + q) * 512 + (r & 15) * 8;
        float s2 = 0.0f;
#pragma unroll
        for (int j = 0; j < 4; ++j) {                       // j = quad-of-k
            const float4 a = ((const float4*)xr)[2 * j];
            const float4 b = ((const float4*)xr)[2 * j + 1];
            const float4 da = ((const float4*)bd)[2 * j];
            const float4 db = ((const float4*)bd)[2 * j + 1];
            float v[8] = {a.x - da.x, a.y - da.y, a.z - da.z, a.w - da.w,
                          b.x - db.x, b.y - db.y, b.z - db.z, b.w - db.w};
            ushort4 p0, p1;
            p0.x = f2bf(v[0]); p0.y = f2bf(v[1]); p0.z = f2bf(v[2]); p0.w = f2bf(v[3]);
            p1.x = f2bf(v[4]); p1.y = f2bf(v[5]); p1.z = f2bf(v[6]); p1.w = f2bf(v[7]);
#pragma unroll
            for (int e = 0; e < 8; ++e) s2 += v[e] * v[e];
            *(ushort4*)(dst + j * 128)     = p0;
            *(ushort4*)(dst + j * 128 + 4) = p1;
        }
        atomicAdd(&thr[r], s2);
    }
    __syncthreads();
    if (tid < MT) {
        const float s2wm = s2w[0] * (1.0f / ((float)H_LAT * (float)D_IN));
        thr[tid] = 2.3f * sqrtf(s2wm * thr[tid]);
    }
    __syncthreads();

    float thrv[4][4];
#pragma unroll
    for (int mt = 0; mt < 4; ++mt)
#pragma unroll
        for (int qi = 0; qi < 4; ++qi) thrv[mt][qi] = thr[mt * 16 + quad * 4 + qi];

    // ---- Phase 1: MFMA K-loop over 2-chunk groups; wave owns 16-col strip ----
    const unsigned short* bp = Wbf + (size_t)(wave * 8) * 512 + lane * 8;
    const unsigned short* ap = A + lane * 8;                // conflict-free A base
    const float* bep = b_enc + wave * 16 + l15;
    int col0 = wave * 16 + l15;

    int pos[4][4];
    auto collect2 = [&](const f32x4 (&a0)[4], const f32x4 (&a1)[4], int cb) {
        const unsigned k0 = (unsigned)(8191 - cb);
        const unsigned k1 = (unsigned)(8191 - (cb + NT));
        // round 1: issue all LDS atomics (one count covers both chunks)
#pragma unroll
        for (int mt = 0; mt < 4; ++mt)
#pragma unroll
            for (int qi = 0; qi < 4; ++qi) {
                const int nadd = (int)(a0[mt][qi] > thrv[mt][qi]) +
                                 (int)(a1[mt][qi] > thrv[mt][qi]);
                pos[mt][qi] = -1000;
                if (nadd)
                    pos[mt][qi] = atomicAdd(&cnt[mt * 16 + quad * 4 + qi], nadd);
            }
        // round 2: predicated packed stores (keys: fp32-bit-order, 2 VALU)
#pragma unroll
        for (int mt = 0; mt < 4; ++mt)
#pragma unroll
            for (int qi = 0; qi < 4; ++qi) {
                const bool p0 = a0[mt][qi] > thrv[mt][qi];
                const bool p1 = a1[mt][qi] > thrv[mt][qi];
                const int r = mt * 16 + quad * 4 + qi;
                int ps = pos[mt][qi];
                if (p0 && (unsigned)ps < CAP)
                    pool[r][ps] = (__float_as_uint(a0[mt][qi]) & 0xFFFFE000u) | k0;
                ps += (int)p0;
                if (p1 && (unsigned)ps < CAP)
                    pool[r][ps] = (__float_as_uint(a1[mt][qi]) & 0xFFFFE000u) | k1;
            }
    };

    for (int g = 0; g < NCH; g += 2) {
        const float bv0 = bep[0], bv1 = bep[NT];            // in flight with loads

        f32x4 acc0[4], acc1[4];
#pragma unroll
        for (int mt = 0; mt < 4; ++mt) {
            acc0[mt] = {bv0, bv0, bv0, bv0};                // C-in = bias
            acc1[mt] = {bv1, bv1, bv1, bv1};
        }

#pragma unroll
        for (int c8 = 0; c8 < 8; ++c8) {
            const bf16x8 a0 = *(const bf16x8*)(ap + (0 * 8 + c8) * 512);
            const bf16x8 a1 = *(const bf16x8*)(ap + (1 * 8 + c8) * 512);
            const bf16x8 a2 = *(const bf16x8*)(ap + (2 * 8 + c8) * 512);
            const bf16x8 a3 = *(const bf16x8*)(ap + (3 * 8 + c8) * 512);
            const bf16x8 w0 = *(const bf16x8*)(bp + c8 * 512);          // chunk g
            const bf16x8 w1 = *(const bf16x8*)(bp + 32768 + c8 * 512);  // chunk g+1
            acc0[0] = __builtin_amdgcn_mfma_f32_16x16x32_bf16(a0, w0, acc0[0], 0, 0, 0);
            acc0[1] = __builtin_amdgcn_mfma_f32_16x16x32_bf16(a1, w0, acc0[1], 0, 0, 0);
            acc0[2] = __builtin_amdgcn_mfma_f32_16x16x32_bf16(a2, w0, acc0[2], 0, 0, 0);
            acc0[3] = __builtin_amdgcn_mfma_f32_16x16x32_bf16(a3, w0, acc0[3], 0, 0, 0);
            acc1[0] = __builtin_amdgcn_mfma_f32_16x16x32_bf16(a0, w1, acc1[0], 0, 0, 0);
            acc1[1] = __builtin_amdgcn_mfma_f32_16x16x32_bf16(a1, w1, acc1[1], 0, 0, 0);
            acc1[2] = __builtin_amdgcn_mfma_f32_16x16x32_bf16(a2, w1, acc1[2], 0, 0, 0);
            acc1[3] = __builtin_amdgcn_mfma_f32_16x16x32_bf16(a3, w1, acc1[3], 0, 0, 0);
        }

        collect2(acc0, acc1, col0);

        bp  += 2 * 32768;                                   // 2 chunks (8 ct16 each)
        bep += 2 * NT;
        col0 += 2 * NT;
    }
    __syncthreads();    // pools complete; A dead -> ext overlays it

    // ---- Phase 2: wave rank-count on packed keys -> top-64 (idx + approx val) ----
    {
        const int rbase = wave * 8;
        for (int rr = 0; rr < 8; ++rr) {
            const int r = rbase + rr;
            const int n = min(cnt[r], CAP);
            unsigned p[3]; int rk[3];
            const int S = (n <= 128) ? 2 : 3;                   // wave-uniform
#pragma unroll
            for (int e = 0; e < 3; ++e) {
                const int c = e * 64 + lane;
                p[e] = (c < n) ? pool[r][c] : (unsigned)(c + 1);  // unique tiny sentinels
                rk[e] = 0;
            }
            if (S == 2) {
                for (int s = 0; s < 64; ++s) {
                    const int src = (lane + s) & 63;
                    const unsigned q0 = (unsigned)__shfl((int)p[0], src, 64);
                    const unsigned q1 = (unsigned)__shfl((int)p[1], src, 64);
                    rk[0] += (q0 > p[0]) + (q1 > p[0]);
                    rk[1] += (q0 > p[1]) + (q1 > p[1]);
                }
            } else {
                for (int s = 0; s < 64; ++s) {
                    const int src = (lane + s) & 63;
#pragma unroll
                    for (int e = 0; e < 3; ++e) {
                        const unsigned q = (unsigned)__shfl((int)p[e], src, 64);
#pragma unroll
                        for (int a = 0; a < 3; ++a) rk[a] += (q > p[a]);
                    }
                }
            }
#pragma unroll
            for (int e = 0; e < 3; ++e) {
                if (e < S && rk[e] < 64) {
                    if (p[e] >= 8192u) {                        // real entry (val>thr -> big key)
                        ext_i[r * 64 + rk[e]] = (unsigned short)(8191 - (p[e] & 0x1fffu));
                        ext_v[r * 64 + rk[e]] = __uint_as_float(p[e] & 0xFFFFE000u);
                    } else {                                    // filler: unique sentinel, val 0
                        ext_i[r * 64 + rk[e]] = (unsigned short)(0x2000 + rk[e]);
                        ext_v[r * 64 + rk[e]] = 0.0f;
                    }
                }
            }
        }
    }
    __syncthreads();

    // ---- Phase 3: exact serial-fmaf rescore of the boundary window only ----
    {
        const int r = tid & 63, c = tid >> 6;                   // 8 threads/row
        const float v32 = ext_v[r * 64 + TOPK - 1];             // approx 32nd value
        __syncthreads();                                        // all read v32 before any writes
        const float* xr = x + (size_t)(row0 + r) * D_IN;
        for (int j = c; j < 64; j += 8) {
            const float va = ext_v[r * 64 + j];
            const int   h  = ext_i[r * 64 + j];
            if (h < H_LAT && fabsf(va - v32) <= DELTA) {
                const float* wr_ = W_enc + (size_t)h * D_IN;
                float s = 0.0f;
                for (int kk = 0; kk < D_IN / 4; ++kk) {         // serial fmaf == np oracle
                    const float4 xv = ((const float4*)xr)[kk];
                    const float4 dv = ((const float4*)b_dec)[kk];
                    const float4 wv = ((const float4*)wr_)[kk];
                    s = fmaf(xv.x - dv.x, wv.x, s);
                    s = fmaf(xv.y - dv.y, wv.y, s);
                    s = fmaf(xv.z - dv.z, wv.z, s);
                    s = fmaf(xv.w - dv.w, wv.w, s);
                }
                ext_v[r * 64 + j] = fmaxf(s + b_enc[h], 0.0f);
            }
        }
    }
    __syncthreads();

    // ---- Phase 4: final rank -> top-32 -> bf16 decoder ----
    {
        const int rbase = wave * 8;
        const float4 bd4 = *(const float4*)&b_dec[lane * 4];
        for (int rr = 0; rr < 8; ++rr) {
            const int r = rbase + rr;
            const float v = ext_v[r * 64 + lane];
            const int   h = ext_i[r * 64 + lane];
            int rank = 0;
            for (int s = 0; s < 64; ++s) {
                const int src = (lane + s) & 63;
                const float wv = __shfl(v, src, 64);
                const int   wh = __shfl(h, src, 64);
                rank += (wv > v) || (wv == v && wh < h);        // val desc, idx asc; keys unique
            }
            if (rank < TOPK) { ext_v[r * 64 + rank] = v; ext_i[r * 64 + rank] = (unsigned short)h; }
            float4 o = bd4;                                     // wave-in-order: writes visible below
#pragma unroll 8
            for (int k = 0; k < TOPK; ++k) {
                const float vv = ext_v[r * 64 + k];             // LDS broadcast
                const int   hh = ext_i[r * 64 + k];
                if (hh < H_LAT) {                               // wave-uniform (guards sentinel)
                    const ushort4 w = *(const ushort4*)&Wdbf[(size_t)hh * D_IN + lane * 4];
                    o.x = fmaf(vv, bf2f(w.x), o.x); o.y = fmaf(vv, bf2f(w.y), o.y);
                    o.z = fmaf(vv, bf2f(w.z), o.z); o.w = fmaf(vv, bf2f(w.w), o.w);
                }
            }
            *(float4*)&out[(size_t)(row0 + r) * D_IN + lane * 4] = o;
        }
    }
}

extern "C" void kernel_launch(void* const* d_in, const int* in_sizes, int n_in,
                              void* d_out, int out_size, void* d_ws, size_t ws_size,
                              hipStream_t stream) {
    const float* x     = (const float*)d_in[0];
    const float* W_enc = (const float*)d_in[1];
    const float* b_enc = (const float*)d_in[2];
    const float* W_dec = (const float*)d_in[3];
    const float* b_dec = (const float*)d_in[4];
    float* out = (float*)d_out;

    const size_t wel = (size_t)H_LAT * D_IN;                    // 2M elements
    float* s2w = (float*)d_ws;                                  // 1 float @ offset 0
    unsigned short* Wbf  = (unsigned short*)((char*)d_ws + 256); // 4 MB bf16 W_enc (swizzled)
    unsigned short* Wdbf = Wbf + wel;                            // 4 MB bf16 W_dec (linear)

    hipMemsetAsync(d_ws, 0, 256, stream);                       // zero s2w (ws is poisoned)
    conv_kernel<<<dim3(1024), dim3(256), 0, stream>>>(W_enc, Wbf, s2w, W_dec, Wdbf);
    sae_main<<<dim3(B_TOK / MT), dim3(512), 0, stream>>>(x, W_enc, b_enc, W_dec, b_dec,
                                                         out, Wbf, s2w, Wdbf);
}

// Round 8
// 532.012 us; speedup vs baseline: 1.2252x; 1.2252x over previous
//
#include <hip/hip_runtime.h>

#define B_TOK 32768
#define D_IN  256
#define H_LAT 8192
#define TOPK  32
#define MT    64          // rows per block
#define NT    128         // h-cols per chunk
#define NCH   (H_LAT / NT)
#define CAP   144         // candidate pool per row (thr=2.3sigma -> lambda~90)
#define DELTA 0.016f      // exact-rescore window; ~8 sigma of bf16-GEMM+pack err

typedef __attribute__((ext_vector_type(4))) float f32x4;
typedef __attribute__((ext_vector_type(8))) short bf16x8;

__device__ __forceinline__ unsigned short f2bf(float f) {   // RNE fp32->bf16
    unsigned u = __float_as_uint(f);
    return (unsigned short)((u + 0x7fffu + ((u >> 16) & 1u)) >> 16);
}
__device__ __forceinline__ float bf2f(unsigned short u) {
    return __uint_as_float((unsigned)u << 16);
}

// Kernel A: W_enc fp32 -> bf16 SWIZZLED to MFMA-fragment order (+ sum W^2);
// W_dec fp32 -> bf16 linear (decoder copy).
// Swizzled layout: dst[((ct16*8 + c8)*64 + lane)*8 + e] =
//   W[ct16*16 + (lane&15)][c8*32 + (lane>>4)*8 + e]
__global__ __launch_bounds__(256)
void conv_kernel(const float* __restrict__ W, unsigned short* __restrict__ Wbf,
                 float* __restrict__ s2w, const float* __restrict__ Wd,
                 unsigned short* __restrict__ Wdbf) {
    const int total4 = (H_LAT * D_IN) / 4;
    float acc = 0.0f;
    for (int j = blockIdx.x * blockDim.x + threadIdx.x; j < total4;
         j += gridDim.x * blockDim.x) {
        const int e4   = j & 1;                 // which half of the 8-elem frag
        const int lane = (j >> 1) & 63;
        const int c8   = (j >> 7) & 7;
        const int ct16 = j >> 10;               // 16-col tile, 0..511
        const int h = ct16 * 16 + (lane & 15);
        const int k = c8 * 32 + (lane >> 4) * 8 + e4 * 4;
        const float4 v = *(const float4*)(W + (size_t)h * D_IN + k);
        acc += v.x * v.x + v.y * v.y + v.z * v.z + v.w * v.w;
        ushort4 o;
        o.x = f2bf(v.x); o.y = f2bf(v.y); o.z = f2bf(v.z); o.w = f2bf(v.w);
        ((ushort4*)Wbf)[j] = o;                 // coalesced write
    }
    for (int i = blockIdx.x * blockDim.x + threadIdx.x; i < total4;
         i += gridDim.x * blockDim.x) {
        const float4 v = ((const float4*)Wd)[i];
        ushort4 o;
        o.x = f2bf(v.x); o.y = f2bf(v.y); o.z = f2bf(v.z); o.w = f2bf(v.w);
        ((ushort4*)Wdbf)[i] = o;
    }
#pragma unroll
    for (int off = 32; off > 0; off >>= 1) acc += __shfl_down(acc, off, 64);
    if ((threadIdx.x & 63) == 0) atomicAdd(s2w, acc);
}

// Kernel B: R6 structure verbatim (512 thr, 8 waves x 16-col strips, two-round
// collect, f2bf keys) with ONE change: A staged in LDS in MFMA-FRAGMENT order,
// so phase-1 A-reads are base + lane*16B with immediate offsets -> zero bank
// conflicts (R6 had 22.2M conflict cycles from 8-way-aliased strided reads).
__global__ __launch_bounds__(512, 4)
void sae_main(const float* __restrict__ x, const float* __restrict__ W_enc,
              const float* __restrict__ b_enc, const float* __restrict__ W_dec,
              const float* __restrict__ b_dec, float* __restrict__ out,
              const unsigned short* __restrict__ Wbf, const float* __restrict__ s2w,
              const unsigned short* __restrict__ Wdbf) {
    // smem: [0, 32768)     A_frag[32][512] ushort (UNION ext_i 8KB + ext_v 16KB)
    //       [32768, 69632) pool[64][144]
    __shared__ __align__(16) char smem[32768 + MT * CAP * 4];
    __shared__ int   cnt[MT];
    __shared__ float thr[MT];

    unsigned short* A = (unsigned short*)smem;
    auto pool = reinterpret_cast<unsigned (*)[CAP]>(smem + 32768);
    unsigned short* ext_i = (unsigned short*)smem;                 // [MT][64] (8 KB)
    float*          ext_v = (float*)(smem + MT * 64 * 2);          // [MT][64] (16 KB)

    const int tid  = threadIdx.x;
    const int row0 = blockIdx.x * MT;
    const int wave = tid >> 6, lane = tid & 63;
    const int l15 = lane & 15, quad = lane >> 4;

    if (tid < MT) { cnt[tid] = 0; thr[tid] = 0.0f; }
    __syncthreads();

    // ---- Phase 0: stage (x - b_dec) -> bf16 LDS in FRAGMENT order ----
    // A[(mt*8 + c8)*512 + (quad*16 + l15)*8 + e] = row mt*16+l15, k=c8*32+quad*8+e
    {
        const int r = tid >> 3, q = tid & 7;                // 8 threads/row, 32 k each
        const float* xr = x + (size_t)(row0 + r) * D_IN + q * 32;
        const float* bd = b_dec + q * 32;
        unsigned short* dst = A + ((r >> 4) * 8 + q) * 512 + (r & 15) * 8;
        float s2 = 0.0f;
#pragma unroll
        for (int j = 0; j < 4; ++j) {                       // j = quad-of-k
            const float4 a = ((const float4*)xr)[2 * j];
            const float4 b = ((const float4*)xr)[2 * j + 1];
            const float4 da = ((const float4*)bd)[2 * j];
            const float4 db = ((const float4*)bd)[2 * j + 1];
            float v[8] = {a.x - da.x, a.y - da.y, a.z - da.z, a.w - da.w,
                          b.x - db.x, b.y - db.y, b.z - db.z, b.w - db.w};
            ushort4 p0, p1;
            p0.x = f2bf(v[0]); p0.y = f2bf(v[1]); p0.z = f2bf(v[2]); p0.w = f2bf(v[3]);
            p1.x = f2bf(v[4]); p1.y = f2bf(v[5]); p1.z = f2bf(v[6]); p1.w = f2bf(v[7]);
#pragma unroll
            for (int e = 0; e < 8; ++e) s2 += v[e] * v[e];
            *(ushort4*)(dst + j * 128)     = p0;
            *(ushort4*)(dst + j * 128 + 4) = p1;
        }
        atomicAdd(&thr[r], s2);
    }
    __syncthreads();
    if (tid < MT) {
        const float s2wm = s2w[0] * (1.0f / ((float)H_LAT * (float)D_IN));
        thr[tid] = 2.3f * sqrtf(s2wm * thr[tid]);
    }
    __syncthreads();

    float thrv[4][4];
#pragma unroll
    for (int mt = 0; mt < 4; ++mt)
#pragma unroll
        for (int qi = 0; qi < 4; ++qi) thrv[mt][qi] = thr[mt * 16 + quad * 4 + qi];

    // ---- Phase 1: MFMA K-loop over 2-chunk groups; wave owns 16-col strip ----
    const unsigned short* bp = Wbf + (size_t)(wave * 8) * 512 + lane * 8;
    const unsigned short* ap = A + lane * 8;                // conflict-free A base
    const float* bep = b_enc + wave * 16 + l15;
    int col0 = wave * 16 + l15;

    // two-round collection: round 1 issues all LDS atomics (no consumer ->
    // no interleaved waits), round 2 does predicated stores after ONE wait.
    int pos[4][4];
    auto collect = [&](const f32x4 (&ac)[4], int cbase) {
        const unsigned colk = (unsigned)(8191 - cbase);
#pragma unroll
        for (int mt = 0; mt < 4; ++mt)
#pragma unroll
            for (int qi = 0; qi < 4; ++qi) {
                pos[mt][qi] = -1;
                if (ac[mt][qi] > thrv[mt][qi])
                    pos[mt][qi] = atomicAdd(&cnt[mt * 16 + quad * 4 + qi], 1);
            }
#pragma unroll
        for (int mt = 0; mt < 4; ++mt)
#pragma unroll
            for (int qi = 0; qi < 4; ++qi) {
                if ((unsigned)pos[mt][qi] < CAP)
                    pool[mt * 16 + quad * 4 + qi][pos[mt][qi]] =
                        ((unsigned)f2bf(ac[mt][qi]) << 13) | colk;
            }
    };

    for (int g = 0; g < NCH; g += 2) {
        const float bv0 = bep[0], bv1 = bep[NT];            // in flight with loads

        f32x4 acc0[4], acc1[4];
#pragma unroll
        for (int mt = 0; mt < 4; ++mt) {
            acc0[mt] = {bv0, bv0, bv0, bv0};                // C-in = bias
            acc1[mt] = {bv1, bv1, bv1, bv1};
        }

#pragma unroll
        for (int c8 = 0; c8 < 8; ++c8) {
            const bf16x8 a0 = *(const bf16x8*)(ap + (0 * 8 + c8) * 512);
            const bf16x8 a1 = *(const bf16x8*)(ap + (1 * 8 + c8) * 512);
            const bf16x8 a2 = *(const bf16x8*)(ap + (2 * 8 + c8) * 512);
            const bf16x8 a3 = *(const bf16x8*)(ap + (3 * 8 + c8) * 512);
            const bf16x8 w0 = *(const bf16x8*)(bp + c8 * 512);          // chunk g
            const bf16x8 w1 = *(const bf16x8*)(bp + 32768 + c8 * 512);  // chunk g+1
            acc0[0] = __builtin_amdgcn_mfma_f32_16x16x32_bf16(a0, w0, acc0[0], 0, 0, 0);
            acc0[1] = __builtin_amdgcn_mfma_f32_16x16x32_bf16(a1, w0, acc0[1], 0, 0, 0);
            acc0[2] = __builtin_amdgcn_mfma_f32_16x16x32_bf16(a2, w0, acc0[2], 0, 0, 0);
            acc0[3] = __builtin_amdgcn_mfma_f32_16x16x32_bf16(a3, w0, acc0[3], 0, 0, 0);
            acc1[0] = __builtin_amdgcn_mfma_f32_16x16x32_bf16(a0, w1, acc1[0], 0, 0, 0);
            acc1[1] = __builtin_amdgcn_mfma_f32_16x16x32_bf16(a1, w1, acc1[1], 0, 0, 0);
            acc1[2] = __builtin_amdgcn_mfma_f32_16x16x32_bf16(a2, w1, acc1[2], 0, 0, 0);
            acc1[3] = __builtin_amdgcn_mfma_f32_16x16x32_bf16(a3, w1, acc1[3], 0, 0, 0);
        }

        collect(acc0, col0);
        collect(acc1, col0 + NT);

        bp  += 2 * 32768;                                   // 2 chunks (8 ct16 each)
        bep += 2 * NT;
        col0 += 2 * NT;
    }
    __syncthreads();    // pools complete; A dead -> ext overlays it

    // ---- Phase 2: wave rank-count on packed keys -> top-64 (idx + approx val) ----
    {
        const int rbase = wave * 8;
        for (int rr = 0; rr < 8; ++rr) {
            const int r = rbase + rr;
            const int n = min(cnt[r], CAP);
            unsigned p[3]; int rk[3];
            const int S = (n <= 128) ? 2 : 3;                   // wave-uniform
#pragma unroll
            for (int e = 0; e < 3; ++e) {
                const int c = e * 64 + lane;
                p[e] = (c < n) ? pool[r][c] : (unsigned)(c + 1);  // unique tiny sentinels
                rk[e] = 0;
            }
            if (S == 2) {
                for (int s = 0; s < 64; ++s) {
                    const int src = (lane + s) & 63;
                    const unsigned q0 = (unsigned)__shfl((int)p[0], src, 64);
                    const unsigned q1 = (unsigned)__shfl((int)p[1], src, 64);
                    rk[0] += (q0 > p[0]) + (q1 > p[0]);
                    rk[1] += (q0 > p[1]) + (q1 > p[1]);
                }
            } else {
                for (int s = 0; s < 64; ++s) {
                    const int src = (lane + s) & 63;
#pragma unroll
                    for (int e = 0; e < 3; ++e) {
                        const unsigned q = (unsigned)__shfl((int)p[e], src, 64);
#pragma unroll
                        for (int a = 0; a < 3; ++a) rk[a] += (q > p[a]);
                    }
                }
            }
#pragma unroll
            for (int e = 0; e < 3; ++e) {
                if (e < S && rk[e] < 64) {
                    if (p[e] >= 8192u) {                        // real entry (val>thr -> big key)
                        ext_i[r * 64 + rk[e]] = (unsigned short)(8191 - (p[e] & 0x1fffu));
                        ext_v[r * 64 + rk[e]] = __uint_as_float((p[e] >> 13) << 16);
                    } else {                                    // filler: unique sentinel, val 0
                        ext_i[r * 64 + rk[e]] = (unsigned short)(0x2000 + rk[e]);
                        ext_v[r * 64 + rk[e]] = 0.0f;
                    }
                }
            }
        }
    }
    __syncthreads();

    // ---- Phase 3: exact serial-fmaf rescore of the boundary window only ----
    {
        const int r = tid & 63, c = tid >> 6;                   // 8 threads/row
        const float v32 = ext_v[r * 64 + TOPK - 1];             // approx 32nd value
        __syncthreads();                                        // all read v32 before any writes
        const float* xr = x + (size_t)(row0 + r) * D_IN;
        for (int j = c; j < 64; j += 8) {
            const float va = ext_v[r * 64 + j];
            const int   h  = ext_i[r * 64 + j];
            if (h < H_LAT && fabsf(va - v32) <= DELTA) {
                const float* wr_ = W_enc + (size_t)h * D_IN;
                float s = 0.0f;
                for (int kk = 0; kk < D_IN / 4; ++kk) {         // serial fmaf == np oracle
                    const float4 xv = ((const float4*)xr)[kk];
                    const float4 dv = ((const float4*)b_dec)[kk];
                    const float4 wv = ((const float4*)wr_)[kk];
                    s = fmaf(xv.x - dv.x, wv.x, s);
                    s = fmaf(xv.y - dv.y, wv.y, s);
                    s = fmaf(xv.z - dv.z, wv.z, s);
                    s = fmaf(xv.w - dv.w, wv.w, s);
                }
                ext_v[r * 64 + j] = fmaxf(s + b_enc[h], 0.0f);
            }
        }
    }
    __syncthreads();

    // ---- Phase 4: final rank -> top-32 -> bf16 decoder ----
    {
        const int rbase = wave * 8;
        const float4 bd4 = *(const float4*)&b_dec[lane * 4];
        for (int rr = 0; rr < 8; ++rr) {
            const int r = rbase + rr;
            const float v = ext_v[r * 64 + lane];
            const int   h = ext_i[r * 64 + lane];
            int rank = 0;
            for (int s = 0; s < 64; ++s) {
                const int src = (lane + s) & 63;
                const float wv = __shfl(v, src, 64);
                const int   wh = __shfl(h, src, 64);
                rank += (wv > v) || (wv == v && wh < h);        // val desc, idx asc; keys unique
            }
            if (rank < TOPK) { ext_v[r * 64 + rank] = v; ext_i[r * 64 + rank] = (unsigned short)h; }
            float4 o = bd4;                                     // wave-in-order: writes visible below
#pragma unroll 8
            for (int k = 0; k < TOPK; ++k) {
                const float vv = ext_v[r * 64 + k];             // LDS broadcast
                const int   hh = ext_i[r * 64 + k];
                if (hh < H_LAT) {                               // wave-uniform (guards sentinel)
                    const ushort4 w = *(const ushort4*)&Wdbf[(size_t)hh * D_IN + lane * 4];
                    o.x = fmaf(vv, bf2f(w.x), o.x); o.y = fmaf(vv, bf2f(w.y), o.y);
                    o.z = fmaf(vv, bf2f(w.z), o.z); o.w = fmaf(vv, bf2f(w.w), o.w);
                }
            }
            *(float4*)&out[(size_t)(row0 + r) * D_IN + lane * 4] = o;
        }
    }
}

extern "C" void kernel_launch(void* const* d_in, const int* in_sizes, int n_in,
                              void* d_out, int out_size, void* d_ws, size_t ws_size,
                              hipStream_t stream) {
    const float* x     = (const float*)d_in[0];
    const float* W_enc = (const float*)d_in[1];
    const float* b_enc = (const float*)d_in[2];
    const float* W_dec = (const float*)d_in[3];
    const float* b_dec = (const float*)d_in[4];
    float* out = (float*)d_out;

    const size_t wel = (size_t)H_LAT * D_IN;                    // 2M elements
    float* s2w = (float*)d_ws;                                  // 1 float @ offset 0
    unsigned short* Wbf  = (unsigned short*)((char*)d_ws + 256); // 4 MB bf16 W_enc (swizzled)
    unsigned short* Wdbf = Wbf + wel;                            // 4 MB bf16 W_dec (linear)

    hipMemsetAsync(d_ws, 0, 256, stream);                       // zero s2w (ws is poisoned)
    conv_kernel<<<dim3(1024), dim3(256), 0, stream>>>(W_enc, Wbf, s2w, W_dec, Wdbf);
    sae_main<<<dim3(B_TOK / MT), dim3(512), 0, stream>>>(x, W_enc, b_enc, W_dec, b_dec,
                                                         out, Wbf, s2w, Wdbf);
}